// Round 6
// baseline (798.630 us; speedup 1.0000x reference)
//
#include <hip/hip_runtime.h>

#define K_CODES 1024
#define DIM 64
#define B_ 16
#define T_ 8192
#define N_ (B_*T_)          // 131072 vectors
#define EPSF 1e-5f
#define SMARGIN 5e-4f       // score-space margin >= 3x practical mfma error bound

typedef __attribute__((ext_vector_type(8))) short short8;   // 8 bf16 = 4 VGPR
typedef __attribute__((ext_vector_type(4))) float f32x4;

__device__ __forceinline__ unsigned bf16_rne(float f) {
    unsigned u = __float_as_uint(f);
    return (u + 0x7fffu + ((u >> 16) & 1u)) >> 16;
}

// native global_atomic_add_f32 (no CAS loop); device-scope, fire-and-forget
__device__ __forceinline__ void fadd_atomic(float* p, float v) {
    unsafeAtomicAdd(p, v);
}

// ---- prep: e -> bf16 hi/lo tables, fp64 table, half-norms fp64 + fp32 ----
__global__ __launch_bounds__(64) void vq_prep(const float* __restrict__ emb,
                                              double* __restrict__ e64,
                                              double* __restrict__ snh64,
                                              float* __restrict__ snh32,
                                              unsigned short* __restrict__ ehib,
                                              unsigned short* __restrict__ elob) {
    const int k = blockIdx.x;
    const int d = threadIdx.x;
    const float ef = emb[k * DIM + d];
    const unsigned rh = bf16_rne(ef);
    const float hif = __uint_as_float(rh << 16);
    const float lof = ef - hif;                   // exact (Sterbenz)
    const unsigned rl = bf16_rne(lof);
    ehib[k * DIM + d] = (unsigned short)rh;
    elob[k * DIM + d] = (unsigned short)rl;

    const double ed = (double)ef;
    e64[k * DIM + d] = ed;
    double s = ed * ed;
    #pragma unroll
    for (int off = 32; off; off >>= 1) s += __shfl_down(s, off, 64);
    if (d == 0) { snh64[k] = 0.5 * s; snh32[k] = (float)(0.5 * s); }
}

// ---- screen: split-bf16 MFMA scores, per-lane top-2, margin flagging ----
// block = 256 thr = 4 waves; wave = 32 vectors (2 n-tiles of 16); grid 1024.
__global__ __launch_bounds__(256) void vq_screen(const float* __restrict__ x,
                                                 const unsigned short* __restrict__ ehib,
                                                 const unsigned short* __restrict__ elob,
                                                 const float* __restrict__ snh32,
                                                 const float* __restrict__ emb,
                                                 float* __restrict__ out,
                                                 float* __restrict__ dw,
                                                 int* __restrict__ counts,
                                                 int* __restrict__ flagcnt,
                                                 int* __restrict__ flagids) {
    __shared__ int sidx[128];            // per-vector: code index, or -1 = flagged

    const int tid  = threadIdx.x;
    const int wid  = tid >> 6;
    const int lane = tid & 63;
    const int ln15 = lane & 15;
    const int lhi  = lane >> 4;          // 0..3

    const int b    = blockIdx.x >> 6;            // 64 blocks per batch row
    const int tblk = (blockIdx.x & 63) << 7;     // 128 vectors per block
    const int t0   = tblk + wid * 32;            // wave's 32 vectors
    const float* xb = x + ((size_t)b << 19);

    // ---- load X B-fragments (hi/lo), register-resident for whole scan ----
    // frag[nt][s]: lane holds B[k = s*32 + lhi*8 + j, n = ln15] = x[d=k][t0+nt*16+ln15]
    short8 xbh[2][2], xbl[2][2];
    #pragma unroll
    for (int nt = 0; nt < 2; nt++) {
        const int t = t0 + nt * 16 + ln15;
        #pragma unroll
        for (int s = 0; s < 2; s++) {
            #pragma unroll
            for (int j = 0; j < 8; j++) {
                const int d = s * 32 + lhi * 8 + j;
                const float xf = xb[((size_t)d << 13) + t];
                const unsigned rh = bf16_rne(xf);
                const float hif = __uint_as_float(rh << 16);
                const unsigned rl = bf16_rne(xf - hif);
                xbh[nt][s][j] = (short)rh;
                xbl[nt][s][j] = (short)rl;
            }
        }
    }

    float b1[2] = {-1e30f, -1e30f}, b2[2] = {-1e30f, -1e30f};
    int   bi[2] = {0, 0};

    for (int k0 = 0; k0 < K_CODES; k0 += 16) {
        // A-fragments: lane holds A[m = ln15, k = s*32 + lhi*8 + j] = e[k0+ln15][k]
        const size_t arow = ((size_t)(k0 + ln15) << 6) + lhi * 8;
        const short8 ah0 = *(const short8*)(ehib + arow);
        const short8 ah1 = *(const short8*)(ehib + arow + 32);
        const short8 al0 = *(const short8*)(elob + arow);
        const short8 al1 = *(const short8*)(elob + arow + 32);
        const f32x4 snq = *(const f32x4*)(snh32 + k0 + lhi * 4);

        #pragma unroll
        for (int nt = 0; nt < 2; nt++) {
            f32x4 acc = {0.f, 0.f, 0.f, 0.f};
            acc = __builtin_amdgcn_mfma_f32_16x16x32_bf16(ah0, xbh[nt][0], acc, 0, 0, 0);
            acc = __builtin_amdgcn_mfma_f32_16x16x32_bf16(ah1, xbh[nt][1], acc, 0, 0, 0);
            acc = __builtin_amdgcn_mfma_f32_16x16x32_bf16(ah0, xbl[nt][0], acc, 0, 0, 0);
            acc = __builtin_amdgcn_mfma_f32_16x16x32_bf16(ah1, xbl[nt][1], acc, 0, 0, 0);
            acc = __builtin_amdgcn_mfma_f32_16x16x32_bf16(al0, xbh[nt][0], acc, 0, 0, 0);
            acc = __builtin_amdgcn_mfma_f32_16x16x32_bf16(al1, xbh[nt][1], acc, 0, 0, 0);
            // C/D: col = ln15 (vector), row = lhi*4 + r (code) [m89-verified]
            #pragma unroll
            for (int r = 0; r < 4; r++) {
                const float m = acc[r] - snq[r];
                b2[nt] = fmaxf(b2[nt], fminf(b1[nt], m));
                if (m > b1[nt]) { b1[nt] = m; bi[nt] = k0 + lhi * 4 + r; }
            }
        }
    }

    // ---- merge top-2 across the 4 lane-groups holding each column ----
    #pragma unroll
    for (int nt = 0; nt < 2; nt++) {
        float B1 = b1[nt], B2 = b2[nt]; int I = bi[nt];
        #pragma unroll
        for (int off = 16; off <= 32; off <<= 1) {
            const float o1 = __shfl_xor(B1, off, 64);
            const float o2 = __shfl_xor(B2, off, 64);
            const int   oi = __shfl_xor(I,  off, 64);
            const float nb2 = fmaxf(fminf(B1, o1), fmaxf(B2, o2));
            if (o1 > B1 || (o1 == B1 && oi < I)) { B1 = o1; I = oi; }
            B2 = nb2;
        }
        if (lane < 16)
            sidx[wid * 32 + nt * 16 + lane] = (B1 - B2 <= SMARGIN) ? -1 : I;
    }
    __syncthreads();

    // ---- epilogue: lane&31 = vector slot, lane>>5 = dim half ----
    const int vslot = lane & 31;
    const int dh    = lane >> 5;
    const int t     = t0 + vslot;
    const int I     = sidx[wid * 32 + vslot];

    if (I < 0) {
        if (dh == 0) { const int p = atomicAdd(flagcnt, 1); flagids[p] = (b << 13) + t; }
    } else {
        const float* xp = xb + t;
        const float* eq = emb + I * DIM + dh * 32;
        float* op = out + ((size_t)b << 19) + t;
        float* dwp = dw + I * DIM + dh * 32;
        #pragma unroll
        for (int j = 0; j < 32; j++) {
            const int d = dh * 32 + j;
            const float xf = xp[(size_t)d << 13];
            op[(size_t)d << 13] = xf + (eq[j] - xf);   // reference's fp32 x+(q-x)
            fadd_atomic(&dwp[j], xf);
        }
        if (dh == 0) atomicAdd(&counts[I], 1);
    }
}

// ---------------- rescan: one block per flagged vector, exact fp64 ----------
__global__ __launch_bounds__(256) void vq_rescan(const float* __restrict__ x,
                                                 const float* __restrict__ emb,
                                                 const double* __restrict__ e64,
                                                 const double* __restrict__ snh64,
                                                 float* __restrict__ out,
                                                 float* __restrict__ dw,
                                                 int* __restrict__ counts,
                                                 const int* __restrict__ flagcnt,
                                                 const int* __restrict__ flagids) {
    __shared__ double sb[256];
    __shared__ int    si[256];
    const int tid   = threadIdx.x;
    const int cslot = tid >> 2;          // 0..63 code slot (block-wide)
    const int dg    = tid & 3;           // 16-dim group
    const int count = *flagcnt;

    for (int i = blockIdx.x; i < count; i += gridDim.x) {
        const int v = flagids[i];
        const int b = v >> 13, t = v & (T_ - 1);
        const float* xb = x + ((size_t)b << 19) + t;

        double xd[16];
        #pragma unroll
        for (int j = 0; j < 16; j++) xd[j] = (double)xb[(size_t)(dg * 16 + j) << 13];

        double best = -1e300; int bi_ = 0;
        for (int cc = 0; cc < 16; cc++) {
            const int k = cc * 64 + cslot;
            const double* ek = e64 + (size_t)k * DIM + dg * 16;
            double a = 0.0;
            #pragma unroll
            for (int j = 0; j < 16; j++) a = __fma_rn(xd[j], ek[j], a);
            a += __shfl_xor(a, 1, 64);
            a += __shfl_xor(a, 2, 64);   // full dot across 4 dim-groups
            const double m = a - snh64[k];
            if (m > best) { best = m; bi_ = k; }  // ascending k: first-max kept
        }

        __syncthreads();                 // protect sb/si from previous iteration
        sb[tid] = best; si[tid] = bi_;
        __syncthreads();
        for (int s = 128; s > 0; s >>= 1) {
            if (tid < s) {
                const double ob = sb[tid + s]; const int oi = si[tid + s];
                if (ob > sb[tid] || (ob == sb[tid] && oi < si[tid])) {
                    sb[tid] = ob; si[tid] = oi;
                }
            }
            __syncthreads();
        }
        const int I = si[0];

        if (tid < 64) {                  // epilogue: thread = dim
            const float xf = xb[(size_t)tid << 13];
            out[((size_t)b << 19) + ((size_t)tid << 13) + t] = xf + (emb[I * DIM + tid] - xf);
            fadd_atomic(&dw[I * DIM + tid], xf);
            if (tid == 0) atomicAdd(&counts[I], 1);
        }
    }
}

// ---------------- finalize: new_embeddings = dw / cluster_size --------------
__global__ __launch_bounds__(64) void vq_final(const float* __restrict__ dw,
                                               const int* __restrict__ counts,
                                               float* __restrict__ newemb) {
    const int k = blockIdx.x;
    const int d = threadIdx.x;
    const float c = (float)counts[k];
    const float n = 131072.0f;
    const float cluster = (c + EPSF) / (n + 1024.0f * EPSF) * n;
    newemb[k * DIM + d] = dw[k * DIM + d] / cluster;
}

extern "C" void kernel_launch(void* const* d_in, const int* in_sizes, int n_in,
                              void* d_out, int out_size, void* d_ws, size_t ws_size,
                              hipStream_t stream) {
    const float* x   = (const float*)d_in[0];
    const float* emb = (const float*)d_in[1];

    char* ws = (char*)d_ws;
    double*         e64     = (double*)(ws);                  // 524288 B
    double*         snh64   = (double*)(ws + 524288);         //   8192 B
    float*          snh32   = (float*)(ws + 532480);          //   4096 B
    unsigned short* ehib    = (unsigned short*)(ws + 536576); // 131072 B
    unsigned short* elob    = (unsigned short*)(ws + 667648); // 131072 B
    float*          dw      = (float*)(ws + 798720);          // 262144 B
    int*            counts  = (int*)(ws + 1060864);           //   4096 B
    int*            flagcnt = (int*)(ws + 1064960);           //     64 B
    int*            flagids = (int*)(ws + 1065024);           // 524288 B

    float* out    = (float*)d_out;
    float* newemb = out + (size_t)B_ * DIM * T_;

    // zero dw + counts + flagcnt (contiguous) every launch
    hipMemsetAsync(dw, 0, 262144 + 4096 + 64, stream);

    vq_prep<<<K_CODES, 64, 0, stream>>>(emb, e64, snh64, snh32, ehib, elob);
    vq_screen<<<N_ / 128, 256, 0, stream>>>(x, ehib, elob, snh32, emb, out, dw, counts,
                                            flagcnt, flagids);
    vq_rescan<<<512, 256, 0, stream>>>(x, emb, e64, snh64, out, dw, counts,
                                       flagcnt, flagids);
    vq_final<<<K_CODES, 64, 0, stream>>>(dw, counts, newemb);
}

// Round 7
// 272.330 us; speedup vs baseline: 2.9326x; 2.9326x over previous
//
#include <hip/hip_runtime.h>

#define K_CODES 1024
#define DIM 64
#define B_ 16
#define T_ 8192
#define N_ (B_*T_)          // 131072 vectors
#define EPSF 1e-5f
#define SMARGIN 5e-4f       // score-space margin >= 3x practical mfma error bound

typedef __attribute__((ext_vector_type(8))) short short8;   // 8 bf16 = 4 VGPR
typedef __attribute__((ext_vector_type(4))) float f32x4;

__device__ __forceinline__ unsigned bf16_rne(float f) {
    unsigned u = __float_as_uint(f);
    return (u + 0x7fffu + ((u >> 16) & 1u)) >> 16;
}

// ---- prep: e -> bf16 hi/lo tables, fp64 table, half-norms fp64 + fp32 ----
__global__ __launch_bounds__(64) void vq_prep(const float* __restrict__ emb,
                                              double* __restrict__ e64,
                                              double* __restrict__ snh64,
                                              float* __restrict__ snh32,
                                              unsigned short* __restrict__ ehib,
                                              unsigned short* __restrict__ elob) {
    const int k = blockIdx.x;
    const int d = threadIdx.x;
    const float ef = emb[k * DIM + d];
    const unsigned rh = bf16_rne(ef);
    const float hif = __uint_as_float(rh << 16);
    const float lof = ef - hif;                   // exact (Sterbenz)
    const unsigned rl = bf16_rne(lof);
    ehib[k * DIM + d] = (unsigned short)rh;
    elob[k * DIM + d] = (unsigned short)rl;

    const double ed = (double)ef;
    e64[k * DIM + d] = ed;
    double s = ed * ed;
    #pragma unroll
    for (int off = 32; off; off >>= 1) s += __shfl_down(s, off, 64);
    if (d == 0) { snh64[k] = 0.5 * s; snh32[k] = (float)(0.5 * s); }
}

// ---- transpose x[b][d][t] -> xT[b*T+t][d] for the coalesced code-reduce ----
__global__ __launch_bounds__(256) void vq_xt(const float* __restrict__ x,
                                             float* __restrict__ xT) {
    __shared__ float tile[64][65];
    const int bb = blockIdx.x >> 7;           // batch
    const int t0 = (blockIdx.x & 127) << 6;   // 64-t tile
    const int tr = threadIdx.x & 63;
    const int dr = threadIdx.x >> 6;          // 4 rows per pass
    const float* xp = x + ((size_t)bb << 19) + t0;
    #pragma unroll
    for (int i = 0; i < 16; i++) {
        const int d = i * 4 + dr;
        tile[d][tr] = xp[((size_t)d << 13) + tr];
    }
    __syncthreads();
    float* op = xT + (((size_t)bb << 13) + t0) * 64;
    #pragma unroll
    for (int i = 0; i < 16; i++) {
        const int t = i * 4 + dr;
        op[(size_t)t * 64 + tr] = tile[tr][t];
    }
}

// ---- screen: split-bf16 MFMA scores, per-lane top-2, margin flagging ----
// block = 256 thr = 4 waves; wave = 32 vectors (2 n-tiles of 16); grid 1024.
__global__ __launch_bounds__(256) void vq_screen(const float* __restrict__ x,
                                                 const unsigned short* __restrict__ ehib,
                                                 const unsigned short* __restrict__ elob,
                                                 const float* __restrict__ snh32,
                                                 const float* __restrict__ emb,
                                                 float* __restrict__ out,
                                                 int* __restrict__ idx32,
                                                 int* __restrict__ flagcnt,
                                                 int* __restrict__ flagids) {
    __shared__ int sidx[128];            // per-vector: code index, or -1 = flagged

    const int tid  = threadIdx.x;
    const int wid  = tid >> 6;
    const int lane = tid & 63;
    const int ln15 = lane & 15;
    const int lhi  = lane >> 4;          // 0..3

    const int b    = blockIdx.x >> 6;            // 64 blocks per batch row
    const int tblk = (blockIdx.x & 63) << 7;     // 128 vectors per block
    const int t0   = tblk + wid * 32;            // wave's 32 vectors
    const float* xb = x + ((size_t)b << 19);

    // frag[nt][s]: lane holds B[k = s*32 + lhi*8 + j, n = ln15] = x[d=k][t0+nt*16+ln15]
    short8 xbh[2][2], xbl[2][2];
    #pragma unroll
    for (int nt = 0; nt < 2; nt++) {
        const int t = t0 + nt * 16 + ln15;
        #pragma unroll
        for (int s = 0; s < 2; s++) {
            #pragma unroll
            for (int j = 0; j < 8; j++) {
                const int d = s * 32 + lhi * 8 + j;
                const float xf = xb[((size_t)d << 13) + t];
                const unsigned rh = bf16_rne(xf);
                const float hif = __uint_as_float(rh << 16);
                const unsigned rl = bf16_rne(xf - hif);
                xbh[nt][s][j] = (short)rh;
                xbl[nt][s][j] = (short)rl;
            }
        }
    }

    float b1[2] = {-1e30f, -1e30f}, b2[2] = {-1e30f, -1e30f};
    int   bi[2] = {0, 0};

    for (int k0 = 0; k0 < K_CODES; k0 += 16) {
        const size_t arow = ((size_t)(k0 + ln15) << 6) + lhi * 8;
        const short8 ah0 = *(const short8*)(ehib + arow);
        const short8 ah1 = *(const short8*)(ehib + arow + 32);
        const short8 al0 = *(const short8*)(elob + arow);
        const short8 al1 = *(const short8*)(elob + arow + 32);
        const f32x4 snq = *(const f32x4*)(snh32 + k0 + lhi * 4);

        #pragma unroll
        for (int nt = 0; nt < 2; nt++) {
            f32x4 acc = {0.f, 0.f, 0.f, 0.f};
            acc = __builtin_amdgcn_mfma_f32_16x16x32_bf16(ah0, xbh[nt][0], acc, 0, 0, 0);
            acc = __builtin_amdgcn_mfma_f32_16x16x32_bf16(ah1, xbh[nt][1], acc, 0, 0, 0);
            acc = __builtin_amdgcn_mfma_f32_16x16x32_bf16(ah0, xbl[nt][0], acc, 0, 0, 0);
            acc = __builtin_amdgcn_mfma_f32_16x16x32_bf16(ah1, xbl[nt][1], acc, 0, 0, 0);
            acc = __builtin_amdgcn_mfma_f32_16x16x32_bf16(al0, xbh[nt][0], acc, 0, 0, 0);
            acc = __builtin_amdgcn_mfma_f32_16x16x32_bf16(al1, xbh[nt][1], acc, 0, 0, 0);
            // C/D: col = ln15 (vector), row = lhi*4 + r (code) [m89-verified]
            #pragma unroll
            for (int r = 0; r < 4; r++) {
                const float m = acc[r] - snq[r];
                b2[nt] = fmaxf(b2[nt], fminf(b1[nt], m));
                if (m > b1[nt]) { b1[nt] = m; bi[nt] = k0 + lhi * 4 + r; }
            }
        }
    }

    // ---- merge top-2 across the 4 lane-groups holding each column ----
    #pragma unroll
    for (int nt = 0; nt < 2; nt++) {
        float B1 = b1[nt], B2 = b2[nt]; int I = bi[nt];
        #pragma unroll
        for (int off = 16; off <= 32; off <<= 1) {
            const float o1 = __shfl_xor(B1, off, 64);
            const float o2 = __shfl_xor(B2, off, 64);
            const int   oi = __shfl_xor(I,  off, 64);
            const float nb2 = fmaxf(fminf(B1, o1), fmaxf(B2, o2));
            if (o1 > B1 || (o1 == B1 && oi < I)) { B1 = o1; I = oi; }
            B2 = nb2;
        }
        if (lane < 16)
            sidx[wid * 32 + nt * 16 + lane] = (B1 - B2 <= SMARGIN) ? -1 : I;
    }
    __syncthreads();

    // ---- epilogue: lane&31 = vector slot, lane>>5 = dim half; NO atomics ----
    const int vslot = lane & 31;
    const int dh    = lane >> 5;
    const int t     = t0 + vslot;
    const int I     = sidx[wid * 32 + vslot];
    const int v     = (b << 13) + t;

    if (I < 0) {
        if (dh == 0) { const int p = atomicAdd(flagcnt, 1); flagids[p] = v; }
    } else {
        if (dh == 0) idx32[v] = I;
        const float* xp = xb + t;
        const float* eq = emb + I * DIM + dh * 32;
        float* op = out + ((size_t)b << 19) + t;
        #pragma unroll
        for (int j = 0; j < 32; j++) {
            const int d = dh * 32 + j;
            const float xf = xp[(size_t)d << 13];
            op[(size_t)d << 13] = xf + (eq[j] - xf);   // reference's fp32 x+(q-x)
        }
    }
}

// ---------------- rescan: one block per flagged vector, exact fp64 ----------
__global__ __launch_bounds__(256) void vq_rescan(const float* __restrict__ x,
                                                 const float* __restrict__ emb,
                                                 const double* __restrict__ e64,
                                                 const double* __restrict__ snh64,
                                                 float* __restrict__ out,
                                                 int* __restrict__ idx32,
                                                 const int* __restrict__ flagcnt,
                                                 const int* __restrict__ flagids) {
    __shared__ double sb[256];
    __shared__ int    si[256];
    const int tid   = threadIdx.x;
    const int cslot = tid >> 2;          // 0..63 code slot (block-wide)
    const int dg    = tid & 3;           // 16-dim group
    const int count = *flagcnt;

    for (int i = blockIdx.x; i < count; i += gridDim.x) {
        const int v = flagids[i];
        const int b = v >> 13, t = v & (T_ - 1);
        const float* xb = x + ((size_t)b << 19) + t;

        double xd[16];
        #pragma unroll
        for (int j = 0; j < 16; j++) xd[j] = (double)xb[(size_t)(dg * 16 + j) << 13];

        double best = -1e300; int bi_ = 0;
        for (int cc = 0; cc < 16; cc++) {
            const int k = cc * 64 + cslot;
            const double* ek = e64 + (size_t)k * DIM + dg * 16;
            double a = 0.0;
            #pragma unroll
            for (int j = 0; j < 16; j++) a = __fma_rn(xd[j], ek[j], a);
            a += __shfl_xor(a, 1, 64);
            a += __shfl_xor(a, 2, 64);   // full dot across 4 dim-groups
            const double m = a - snh64[k];
            if (m > best) { best = m; bi_ = k; }  // ascending k: first-max kept
        }

        __syncthreads();                 // protect sb/si from previous iteration
        sb[tid] = best; si[tid] = bi_;
        __syncthreads();
        for (int s = 128; s > 0; s >>= 1) {
            if (tid < s) {
                const double ob = sb[tid + s]; const int oi = si[tid + s];
                if (ob > sb[tid] || (ob == sb[tid] && oi < si[tid])) {
                    sb[tid] = ob; si[tid] = oi;
                }
            }
            __syncthreads();
        }
        const int I = si[0];

        if (tid < 64) {                  // epilogue: thread = dim
            const float xf = xb[(size_t)tid << 13];
            out[((size_t)b << 19) + ((size_t)tid << 13) + t] = xf + (emb[I * DIM + tid] - xf);
            if (tid == 0) idx32[v] = I;
        }
    }
}

// ---- hist: per-block LDS histogram of idx32 -> global counts ----
__global__ __launch_bounds__(1024) void vq_hist(const int* __restrict__ idx32,
                                                int* __restrict__ counts) {
    __shared__ int h[K_CODES];
    const int tid = threadIdx.x;
    h[tid] = 0;
    __syncthreads();
    const int base = blockIdx.x * 2048 + tid;
    atomicAdd(&h[idx32[base]], 1);
    atomicAdd(&h[idx32[base + 1024]], 1);
    __syncthreads();
    const int c = h[tid];
    if (c) atomicAdd(&counts[tid], c);
}

// ---- scan: exclusive prefix sum of counts -> offsets, cursors ----
__global__ __launch_bounds__(1024) void vq_scan(const int* __restrict__ counts,
                                                int* __restrict__ offsets,
                                                int* __restrict__ cursors) {
    __shared__ int s[K_CODES];
    const int tid = threadIdx.x;
    const int c0 = counts[tid];
    int incl = c0;
    s[tid] = incl;
    __syncthreads();
    for (int off = 1; off < K_CODES; off <<= 1) {
        const int add = (tid >= off) ? s[tid - off] : 0;
        __syncthreads();
        incl += add;
        s[tid] = incl;
        __syncthreads();
    }
    const int excl = incl - c0;
    offsets[tid] = excl;
    cursors[tid] = excl;
}

// ---- scatter: counting-sort vector ids by code ----
__global__ __launch_bounds__(256) void vq_scatter(const int* __restrict__ idx32,
                                                  int* __restrict__ cursors,
                                                  int* __restrict__ order) {
    const int v = blockIdx.x * 256 + threadIdx.x;
    const int k = idx32[v];
    const int p = atomicAdd(&cursors[k], 1);
    order[p] = v;
}

// ---- reduce: block per code; sum assigned x, divide by cluster_size ----
__global__ __launch_bounds__(64) void vq_reduce(const float* __restrict__ x,
                                                const float* __restrict__ xT,
                                                const int* __restrict__ order,
                                                const int* __restrict__ offsets,
                                                const int* __restrict__ counts,
                                                float* __restrict__ newemb,
                                                int use_xt) {
    __shared__ int lv[2048];
    const int k = blockIdx.x;
    const int d = threadIdx.x;
    const int off = offsets[k];
    const int cnt = counts[k];
    float sum = 0.f;
    for (int base = 0; base < cnt; base += 2048) {
        const int m = min(2048, cnt - base);
        __syncthreads();
        for (int i = d; i < m; i += 64) lv[i] = order[off + base + i];
        __syncthreads();
        if (use_xt) {
            for (int i = 0; i < m; i++) sum += xT[(size_t)lv[i] * 64 + d];
        } else {
            for (int i = 0; i < m; i++) {
                const int v = lv[i];
                sum += x[((size_t)(v >> 13) << 19) + ((size_t)d << 13) + (v & (T_ - 1))];
            }
        }
    }
    const float c = (float)cnt;
    const float cluster = (c + EPSF) / (131072.0f + 1024.0f * EPSF) * 131072.0f;
    newemb[k * DIM + d] = sum / cluster;
}

extern "C" void kernel_launch(void* const* d_in, const int* in_sizes, int n_in,
                              void* d_out, int out_size, void* d_ws, size_t ws_size,
                              hipStream_t stream) {
    const float* x   = (const float*)d_in[0];
    const float* emb = (const float*)d_in[1];

    char* ws = (char*)d_ws;
    double*         e64     = (double*)(ws);                  //  524288 B
    double*         snh64   = (double*)(ws + 524288);         //    8192 B
    float*          snh32   = (float*)(ws + 532480);          //    4096 B
    unsigned short* ehib    = (unsigned short*)(ws + 536576); //  131072 B
    unsigned short* elob    = (unsigned short*)(ws + 667648); //  131072 B
    int*            idx32   = (int*)(ws + 798720);            //  524288 B
    int*            order   = (int*)(ws + 1323008);           //  524288 B
    int*            counts  = (int*)(ws + 1847296);           //    4096 B
    int*            flagcnt = (int*)(ws + 1851392);           //      64 B
    int*            offsets = (int*)(ws + 1851456);           //    4096 B
    int*            cursors = (int*)(ws + 1855552);           //    4096 B
    int*            flagids = (int*)(ws + 1859648);           //  524288 B
    float*          xT      = (float*)(ws + 2383936);         // 33554432 B (optional)
    const int use_xt = (ws_size >= (size_t)2383936 + 33554432) ? 1 : 0;

    float* out    = (float*)d_out;
    float* newemb = out + (size_t)B_ * DIM * T_;

    // zero counts + flagcnt (contiguous) every launch
    hipMemsetAsync(counts, 0, 4096 + 64, stream);

    vq_prep<<<K_CODES, 64, 0, stream>>>(emb, e64, snh64, snh32, ehib, elob);
    if (use_xt) vq_xt<<<2048, 256, 0, stream>>>(x, xT);
    vq_screen<<<N_ / 128, 256, 0, stream>>>(x, ehib, elob, snh32, emb, out, idx32,
                                            flagcnt, flagids);
    vq_rescan<<<512, 256, 0, stream>>>(x, emb, e64, snh64, out, idx32,
                                       flagcnt, flagids);
    vq_hist<<<N_ / 2048, 1024, 0, stream>>>(idx32, counts);
    vq_scan<<<1, 1024, 0, stream>>>(counts, offsets, cursors);
    vq_scatter<<<N_ / 256, 256, 0, stream>>>(idx32, cursors, order);
    vq_reduce<<<K_CODES, 64, 0, stream>>>(x, xT, order, offsets, counts, newemb, use_xt);
}